// Round 8
// baseline (540.225 us; speedup 1.0000x reference)
//
#include <hip/hip_runtime.h>
#include <hip/hip_bf16.h>
#include <stdint.h>

// CompressedLinear: out[M][N] = x[M][K] @ (w_int8[N][K] * scale[N])^T + bias[N]
// M=8192, K=4096, N=11008.
// R8: i8 GEMM, 32x32x32 MFMA, ZERO LDS / ZERO barriers. Both operands pre-packed
// frag-linear in d_ws; every wave streams its fragments global(L2)->VGPR with a
// 2-slice register pipeline and MFMAs. Waves free-run (natural de-phasing).

#define MT 8192
#define KT 4096
#define NT 11008
#define NKT 32              // K tiles of 128 (i8)
#define MTILES 32           // 8192/256
#define NTILES 86           // 11008/128
#define CHUNK_A 32768       // 256 rows x 128 k
#define CHUNK_B 16384       // 128 cols x 128 k

typedef __attribute__((ext_vector_type(8))) short short8;
typedef __attribute__((ext_vector_type(4))) float f32x4;
typedef __attribute__((ext_vector_type(4))) int i32x4;
typedef __attribute__((ext_vector_type(16))) int i32x16;
typedef __attribute__((ext_vector_type(16))) char char16;

static __device__ __forceinline__ short f2bf(float f) {
  union { float f; unsigned u; } c; c.f = f;
  unsigned u = c.u;
  return (short)((u + 0x7fffu + ((u >> 16) & 1u)) >> 16);  // RNE
}

// ---------------- packers: FRAG-LINEAR layout (R7-verified) ----------------
// A chunk (mt, kt) 32KB: frag(r32 0..7, s 0..3) at (r32*4+s)*1024; lane l holds
// row = mt*256 + r32*32 + (l&31), k = kt*128 + s*32 + (l>>5)*16 .. +15.
__global__ __launch_bounds__(256) void quant_x_kernel(const float* __restrict__ in,
                                                      char* __restrict__ Aws,
                                                      float* __restrict__ sx) {
  const int m = blockIdx.x;
  const int t = threadIdx.x;  // handles k = t*16 .. +15
  const float* row = in + (size_t)m * KT + t * 16;
  f32x4 v[4];
  float mx = 0.f;
#pragma unroll
  for (int i = 0; i < 4; i++) {
    v[i] = *(const f32x4*)(row + i * 4);
#pragma unroll
    for (int j = 0; j < 4; j++) mx = fmaxf(mx, fabsf(v[i][j]));
  }
#pragma unroll
  for (int off = 32; off; off >>= 1) mx = fmaxf(mx, __shfl_xor(mx, off));
  __shared__ float smx[4];
  if ((t & 63) == 0) smx[t >> 6] = mx;
  __syncthreads();
  mx = fmaxf(fmaxf(smx[0], smx[1]), fmaxf(smx[2], smx[3]));
  const float inv = 127.0f / mx;
  if (t == 0) sx[m] = mx * (1.0f / 127.0f);
  char16 q;
#pragma unroll
  for (int i = 0; i < 4; i++)
#pragma unroll
    for (int j = 0; j < 4; j++) q[i * 4 + j] = (char)(int)rintf(v[i][j] * inv);
  const int kt = t >> 3, s = (t >> 1) & 3, hi = t & 1;
  const int lane = (m & 31) | (hi << 5);
  const int r32 = (m >> 5) & 7;
  *(char16*)(Aws + ((size_t)(m >> 8) * NKT + kt) * CHUNK_A +
             (r32 * 4 + s) * 1024 + lane * 16) = q;
}

// B chunk (nt, kt) 16KB: frag(c32 0..3, s 0..3) at (c32*4+s)*1024; lane l holds
// col = nt*128 + c32*32 + (l&31), k = kt*128 + s*32 + (l>>5)*16 .. +15.
__global__ __launch_bounds__(256) void cvt_w8_kernel(const int* __restrict__ in,
                                                     char* __restrict__ Bws) {
  const int n = blockIdx.x;
  const int t = threadIdx.x;
  const int* s_ = in + (size_t)n * KT + t * 16;
  char16 q;
#pragma unroll
  for (int i = 0; i < 4; i++) {
    i32x4 a = *(const i32x4*)(s_ + i * 4);
#pragma unroll
    for (int j = 0; j < 4; j++) q[i * 4 + j] = (char)a[j];
  }
  const int kt = t >> 3, s = (t >> 1) & 3, hi = t & 1;
  const int lane = (n & 31) | (hi << 5);
  const int c32 = (n >> 5) & 3;
  *(char16*)(Bws + ((size_t)(n >> 7) * NKT + kt) * CHUNK_B +
             (c32 * 4 + s) * 1024 + lane * 16) = q;
}

// ---------------- 256x128 i8 GEMM, 4 independent waves, no LDS ----------------
// Waves (2x2): wr=wid>>1 (M half), wc=wid&1 (N half); per-wave 128x64 = 4x2
// frags of 32x32 (acc 128). Slice stream u = kt*4+s (0..127); per slice:
// 4 A + 2 B global_load_dwordx4 (frag-linear, L2-resident) + 8 MFMA.
// 2 register buffers; load(u+2) issued after MMS(u) -> effective depth 2.
// Final slices read <=8KB past the stream end: lands in B/sx regions (mapped).

// load slice u into buffer (A_, B_)
#define LOADSL(u, A_, B_)                                                \
  do {                                                                   \
    const char* ab_ = Abase + (((u) >> 2) * CHUNK_A + ((u)&3) * 1024);   \
    A_[0] = *(const i32x4*)(ab_);                                        \
    A_[1] = *(const i32x4*)(ab_ + 4096);                                 \
    A_[2] = *(const i32x4*)(ab_ + 8192);                                 \
    A_[3] = *(const i32x4*)(ab_ + 12288);                                \
    const char* bb_ = Bbase + (((u) >> 2) * CHUNK_B + ((u)&3) * 1024);   \
    B_[0] = *(const i32x4*)(bb_);                                        \
    B_[1] = *(const i32x4*)(bb_ + 4096);                                 \
  } while (0)

#define MMS(A_, B_)                                                            \
  do {                                                                         \
    __builtin_amdgcn_s_setprio(1);                                             \
    _Pragma("unroll") for (int mb = 0; mb < 4; mb++)                           \
        _Pragma("unroll") for (int nb = 0; nb < 2; nb++)                       \
            acc[mb][nb] = __builtin_amdgcn_mfma_i32_32x32x32_i8(               \
                A_[mb], B_[nb], acc[mb][nb], 0, 0, 0);                         \
    __builtin_amdgcn_s_setprio(0);                                             \
  } while (0)

__global__ __launch_bounds__(256, 2) void gemm_nolds(
    const char* __restrict__ Aws, const char* __restrict__ Bws,
    const float* __restrict__ sx, const float* __restrict__ scale,
    const float* __restrict__ bias, float* __restrict__ out) {
  const int tid = threadIdx.x;
  const int lane = tid & 63;
  const int wid = tid >> 6;
  const int wr = wid >> 1;
  const int wc = wid & 1;

  // XCD mapping: nwg = 32*86 = 2752 = 8 XCD x 344; band = 4 mt x 86 nt.
  // mt-minor (4 consecutive share a B chunk), nt-major. A band 4MB -> L2/XCD.
  const int bid = blockIdx.x;
  const int r = bid >> 3;
  const int mt = (bid & 7) * 4 + (r & 3);  // 0..31
  const int nt = r >> 2;                   // 0..85

  // frag-linear per-wave stream bases
  const char* Abase = Aws + (size_t)mt * NKT * CHUNK_A + wr * 16384 + lane * 16;
  const char* Bbase = Bws + (size_t)nt * NKT * CHUNK_B + wc * 8192 + lane * 16;

  i32x16 acc[4][2] = {};
  i32x4 aP[4], bP[2], aQ[4], bQ[2];

  LOADSL(0, aP, bP);
  LOADSL(1, aQ, bQ);

  for (int t = 0; t < NKT; ++t) {
    const int u = t * 4;
    MMS(aP, bP);  LOADSL(u + 2, aP, bP);
    MMS(aQ, bQ);  LOADSL(u + 3, aQ, bQ);
    MMS(aP, bP);  LOADSL(u + 4, aP, bP);
    MMS(aQ, bQ);  LOADSL(u + 5, aQ, bQ);
  }

  // ---- epilogue: 32x32 C/D (m74/m101): col=lane&31, row=(reg&3)+8*(reg>>2)+4*(lane>>5) ----
  const int col_base = nt * 128 + wc * 64 + (lane & 31);
  const int row0 = mt * 256 + wr * 128 + ((lane >> 5) << 2);
#pragma unroll
  for (int mb = 0; mb < 4; mb++) {
    f32x4 sxq[4];
#pragma unroll
    for (int g = 0; g < 4; g++)
      sxq[g] = *(const f32x4*)(sx + row0 + mb * 32 + g * 8);
#pragma unroll
    for (int nb = 0; nb < 2; nb++) {
      const int n = col_base + nb * 32;
      const float sc = scale[n];
      const float bs = bias[n];
#pragma unroll
      for (int g = 0; g < 4; g++)
#pragma unroll
        for (int j = 0; j < 4; j++) {
          const int row = row0 + mb * 32 + g * 8 + j;
          out[(size_t)row * NT + n] =
              (float)acc[mb][nb][g * 4 + j] * (sxq[g][j] * sc) + bs;
        }
    }
  }
}

// ---------- fallback (raw inputs, fused bf16 convert; round-1 structure) ----------
__global__ __launch_bounds__(256) void gemm_fallback(
    const float* __restrict__ Ap, const int* __restrict__ Bp,
    const float* __restrict__ scale, const float* __restrict__ bias,
    float* __restrict__ out) {
  __shared__ short ldsA[128 * 64];
  __shared__ short ldsB[128 * 64];
  const int tid = threadIdx.x;
  const int lane = tid & 63;
  const int wid = tid >> 6;
  const int nbn = NT / 128;
  const int cpx = ((MT / 128) * nbn) / 8;
  const int bid = blockIdx.x;
  const int wg = (bid & 7) * cpx + (bid >> 3);
  const int brow = (wg / nbn) * 128;
  const int bcol = (wg % nbn) * 128;
  const int wr = wid >> 1, wc = wid & 1;
  f32x4 acc[4][4] = {{{0.f, 0.f, 0.f, 0.f}}};
  const int srow = tid >> 3;
  const int sk8 = (tid & 7) * 8;
  for (int k0 = 0; k0 < KT; k0 += 64) {
    __syncthreads();
#pragma unroll
    for (int p = 0; p < 4; p++) {
      const int row = p * 32 + srow;
      const float* s = Ap + (size_t)(brow + row) * KT + k0 + sk8;
      f32x4 lo = *(const f32x4*)s;
      f32x4 hi = *(const f32x4*)(s + 4);
      short8 v;
#pragma unroll
      for (int j = 0; j < 4; j++) { v[j] = f2bf(lo[j]); v[4 + j] = f2bf(hi[j]); }
      int bo = (row * 64 + sk8) * 2;
      bo ^= ((row & 7) << 4);
      *(short8*)((char*)ldsA + bo) = v;
    }
#pragma unroll
    for (int p = 0; p < 4; p++) {
      const int row = p * 32 + srow;
      const int* s = Bp + (size_t)(bcol + row) * KT + k0 + sk8;
      i32x4 lo = *(const i32x4*)(s);
      i32x4 hi = *(const i32x4*)(s + 4);
      short8 v;
#pragma unroll
      for (int j = 0; j < 4; j++) { v[j] = f2bf((float)lo[j]); v[4 + j] = f2bf((float)hi[j]); }
      int bo = (row * 64 + sk8) * 2;
      bo ^= ((row & 7) << 4);
      *(short8*)((char*)ldsB + bo) = v;
    }
    __syncthreads();
#pragma unroll
    for (int kk = 0; kk < 2; kk++) {
      short8 af[4], bf2[4];
#pragma unroll
      for (int mi = 0; mi < 4; mi++) {
        const int row = wr * 64 + mi * 16 + (lane & 15);
        int bo = (row * 64 + kk * 32 + (lane >> 4) * 8) * 2;
        bo ^= ((row & 7) << 4);
        af[mi] = *(const short8*)((const char*)ldsA + bo);
      }
#pragma unroll
      for (int ni = 0; ni < 4; ni++) {
        const int row = wc * 64 + ni * 16 + (lane & 15);
        int bo = (row * 64 + kk * 32 + (lane >> 4) * 8) * 2;
        bo ^= ((row & 7) << 4);
        bf2[ni] = *(const short8*)((const char*)ldsB + bo);
      }
#pragma unroll
      for (int mi = 0; mi < 4; mi++)
#pragma unroll
        for (int ni = 0; ni < 4; ni++)
          acc[mi][ni] = __builtin_amdgcn_mfma_f32_16x16x32_bf16(af[mi], bf2[ni],
                                                                acc[mi][ni], 0, 0, 0);
    }
  }
#pragma unroll
  for (int ni = 0; ni < 4; ni++) {
    const int n = bcol + wc * 64 + ni * 16 + (lane & 15);
    const float sc = scale[n];
    const float bs = bias[n];
#pragma unroll
    for (int mi = 0; mi < 4; mi++) {
      const int m0 = brow + wr * 64 + mi * 16 + ((lane >> 4) << 2);
#pragma unroll
      for (int j = 0; j < 4; j++)
        out[(size_t)(m0 + j) * NT + n] = acc[mi][ni][j] * sc + bs;
    }
  }
}

extern "C" void kernel_launch(void* const* d_in, const int* in_sizes, int n_in,
                              void* d_out, int out_size, void* d_ws, size_t ws_size,
                              hipStream_t stream) {
  const float* x = (const float*)d_in[0];
  const int* w = (const int*)d_in[1];
  const float* scale = (const float*)d_in[2];
  const float* bias = (const float*)d_in[3];
  float* out = (float*)d_out;

  const size_t a_bytes = (size_t)MTILES * NKT * CHUNK_A;  // 32 MB
  const size_t b_bytes = (size_t)NTILES * NKT * CHUNK_B;  // 43 MB
  const size_t s_bytes = (size_t)MT * sizeof(float);      // 32 KB

  if (ws_size >= a_bytes + b_bytes + s_bytes) {
    char* aw = (char*)d_ws;
    char* bw = aw + a_bytes;
    float* sx = (float*)(bw + b_bytes);
    quant_x_kernel<<<dim3(MT), dim3(256), 0, stream>>>(x, aw, sx);
    cvt_w8_kernel<<<dim3(NT), dim3(256), 0, stream>>>(w, bw);
    gemm_nolds<<<dim3(MTILES * NTILES), dim3(256), 0, stream>>>(
        aw, bw, sx, scale, bias, out);
  } else {
    gemm_fallback<<<dim3((MT / 128) * (NT / 128)), dim3(256), 0, stream>>>(
        x, w, scale, bias, out);
  }
}

// Round 9
// 539.380 us; speedup vs baseline: 1.0016x; 1.0016x over previous
//
#include <hip/hip_runtime.h>
#include <hip/hip_bf16.h>
#include <stdint.h>

// CompressedLinear: out[M][N] = x[M][K] @ (w_int8[N][K] * scale[N])^T + bias[N]
// M=8192, K=4096, N=11008.
// R9: i8 GEMM, 32x32x32 MFMA, no LDS / no barriers (R8 structure) +
//   (a) NON-TEMPORAL output stores: 360MB write stream no longer thrashes the
//       LLC -> 75MB pre-packed operands stay LLC-resident (FETCH was 5x).
//   (b) depth-4 register pipeline (P/Q/R/S, one K-tile per body, static names).

#define MT 8192
#define KT 4096
#define NT 11008
#define NKT 32              // K tiles of 128 (i8)
#define MTILES 32           // 8192/256
#define NTILES 86           // 11008/128
#define CHUNK_A 32768       // 256 rows x 128 k
#define CHUNK_B 16384       // 128 cols x 128 k

typedef __attribute__((ext_vector_type(8))) short short8;
typedef __attribute__((ext_vector_type(4))) float f32x4;
typedef __attribute__((ext_vector_type(4))) int i32x4;
typedef __attribute__((ext_vector_type(16))) int i32x16;
typedef __attribute__((ext_vector_type(16))) char char16;

static __device__ __forceinline__ short f2bf(float f) {
  union { float f; unsigned u; } c; c.f = f;
  unsigned u = c.u;
  return (short)((u + 0x7fffu + ((u >> 16) & 1u)) >> 16);  // RNE
}

// ---------------- packers: FRAG-LINEAR layout (R7-verified) ----------------
// A chunk (mt, kt) 32KB: frag(r32 0..7, s 0..3) at (r32*4+s)*1024; lane l holds
// row = mt*256 + r32*32 + (l&31), k = kt*128 + s*32 + (l>>5)*16 .. +15.
__global__ __launch_bounds__(256) void quant_x_kernel(const float* __restrict__ in,
                                                      char* __restrict__ Aws,
                                                      float* __restrict__ sx) {
  const int m = blockIdx.x;
  const int t = threadIdx.x;  // handles k = t*16 .. +15
  const float* row = in + (size_t)m * KT + t * 16;
  f32x4 v[4];
  float mx = 0.f;
#pragma unroll
  for (int i = 0; i < 4; i++) {
    v[i] = *(const f32x4*)(row + i * 4);
#pragma unroll
    for (int j = 0; j < 4; j++) mx = fmaxf(mx, fabsf(v[i][j]));
  }
#pragma unroll
  for (int off = 32; off; off >>= 1) mx = fmaxf(mx, __shfl_xor(mx, off));
  __shared__ float smx[4];
  if ((t & 63) == 0) smx[t >> 6] = mx;
  __syncthreads();
  mx = fmaxf(fmaxf(smx[0], smx[1]), fmaxf(smx[2], smx[3]));
  const float inv = 127.0f / mx;
  if (t == 0) sx[m] = mx * (1.0f / 127.0f);
  char16 q;
#pragma unroll
  for (int i = 0; i < 4; i++)
#pragma unroll
    for (int j = 0; j < 4; j++) q[i * 4 + j] = (char)(int)rintf(v[i][j] * inv);
  const int kt = t >> 3, s = (t >> 1) & 3, hi = t & 1;
  const int lane = (m & 31) | (hi << 5);
  const int r32 = (m >> 5) & 7;
  *(char16*)(Aws + ((size_t)(m >> 8) * NKT + kt) * CHUNK_A +
             (r32 * 4 + s) * 1024 + lane * 16) = q;
}

// B chunk (nt, kt) 16KB: frag(c32 0..3, s 0..3) at (c32*4+s)*1024; lane l holds
// col = nt*128 + c32*32 + (l&31), k = kt*128 + s*32 + (l>>5)*16 .. +15.
__global__ __launch_bounds__(256) void cvt_w8_kernel(const int* __restrict__ in,
                                                     char* __restrict__ Bws) {
  const int n = blockIdx.x;
  const int t = threadIdx.x;
  const int* s_ = in + (size_t)n * KT + t * 16;
  char16 q;
#pragma unroll
  for (int i = 0; i < 4; i++) {
    i32x4 a = *(const i32x4*)(s_ + i * 4);
#pragma unroll
    for (int j = 0; j < 4; j++) q[i * 4 + j] = (char)a[j];
  }
  const int kt = t >> 3, s = (t >> 1) & 3, hi = t & 1;
  const int lane = (n & 31) | (hi << 5);
  const int c32 = (n >> 5) & 3;
  *(char16*)(Bws + ((size_t)(n >> 7) * NKT + kt) * CHUNK_B +
             (c32 * 4 + s) * 1024 + lane * 16) = q;
}

// ---------------- 256x128 i8 GEMM, 4 independent waves, no LDS ----------------
// Waves (2x2): wr=wid>>1 (M half), wc=wid&1 (N half); per-wave 128x64 = 4x2
// frags of 32x32 (acc 128). Slice stream u = kt*4+s (0..127); per slice:
// 4 A + 2 B global_load_dwordx4 (frag-linear, LLC-resident) + 8 MFMA.
// Depth-4 pipeline: buffers P,Q,R,S; load(u+4) issued after MMS(u) -> ~3 slices
// (~2300 cyc) of latency coverage. Final tile prefetches <=16KB past stream end:
// lands in B region / sx buffer (mapped, read-only). Waves free-run: no barriers.

#define LOADSL(u, A_, B_)                                                \
  do {                                                                   \
    const char* ab_ = Abase + (((u) >> 2) * CHUNK_A + ((u)&3) * 1024);   \
    A_[0] = *(const i32x4*)(ab_);                                        \
    A_[1] = *(const i32x4*)(ab_ + 4096);                                 \
    A_[2] = *(const i32x4*)(ab_ + 8192);                                 \
    A_[3] = *(const i32x4*)(ab_ + 12288);                                \
    const char* bb_ = Bbase + (((u) >> 2) * CHUNK_B + ((u)&3) * 1024);   \
    B_[0] = *(const i32x4*)(bb_);                                        \
    B_[1] = *(const i32x4*)(bb_ + 4096);                                 \
  } while (0)

#define MMS(A_, B_)                                                            \
  do {                                                                         \
    __builtin_amdgcn_s_setprio(1);                                             \
    _Pragma("unroll") for (int mb = 0; mb < 4; mb++)                           \
        _Pragma("unroll") for (int nb = 0; nb < 2; nb++)                       \
            acc[mb][nb] = __builtin_amdgcn_mfma_i32_32x32x32_i8(               \
                A_[mb], B_[nb], acc[mb][nb], 0, 0, 0);                         \
    __builtin_amdgcn_s_setprio(0);                                             \
  } while (0)

__global__ __launch_bounds__(256, 2) void gemm_nolds(
    const char* __restrict__ Aws, const char* __restrict__ Bws,
    const float* __restrict__ sx, const float* __restrict__ scale,
    const float* __restrict__ bias, float* __restrict__ out) {
  const int tid = threadIdx.x;
  const int lane = tid & 63;
  const int wid = tid >> 6;
  const int wr = wid >> 1;
  const int wc = wid & 1;

  // XCD mapping: nwg = 32*86 = 2752 = 8 XCD x 344; band = 4 mt x 86 nt.
  // mt-minor (4 consecutive share a B chunk), nt-major.
  const int bid = blockIdx.x;
  const int r = bid >> 3;
  const int mt = (bid & 7) * 4 + (r & 3);  // 0..31
  const int nt = r >> 2;                   // 0..85

  // frag-linear per-wave stream bases
  const char* Abase = Aws + (size_t)mt * NKT * CHUNK_A + wr * 16384 + lane * 16;
  const char* Bbase = Bws + (size_t)nt * NKT * CHUNK_B + wc * 8192 + lane * 16;

  i32x16 acc[4][2] = {};
  i32x4 aP[4], bP[2], aQ[4], bQ[2], aR[4], bR[2], aS[4], bS[2];

  LOADSL(0, aP, bP);
  LOADSL(1, aQ, bQ);
  LOADSL(2, aR, bR);
  LOADSL(3, aS, bS);

  for (int t = 0; t < NKT; ++t) {
    const int u = t * 4;
    MMS(aP, bP);  LOADSL(u + 4, aP, bP);
    MMS(aQ, bQ);  LOADSL(u + 5, aQ, bQ);
    MMS(aR, bR);  LOADSL(u + 6, aR, bR);
    MMS(aS, bS);  LOADSL(u + 7, aS, bS);
  }

  // ---- epilogue: 32x32 C/D (m74/m101): col=lane&31, row=(reg&3)+8*(reg>>2)+4*(lane>>5)
  //      NON-TEMPORAL stores: keep the 360MB output stream out of L2/LLC. ----
  const int col_base = nt * 128 + wc * 64 + (lane & 31);
  const int row0 = mt * 256 + wr * 128 + ((lane >> 5) << 2);
#pragma unroll
  for (int mb = 0; mb < 4; mb++) {
    f32x4 sxq[4];
#pragma unroll
    for (int g = 0; g < 4; g++)
      sxq[g] = *(const f32x4*)(sx + row0 + mb * 32 + g * 8);
#pragma unroll
    for (int nb = 0; nb < 2; nb++) {
      const int n = col_base + nb * 32;
      const float sc = scale[n];
      const float bs = bias[n];
#pragma unroll
      for (int g = 0; g < 4; g++)
#pragma unroll
        for (int j = 0; j < 4; j++) {
          const int row = row0 + mb * 32 + g * 8 + j;
          __builtin_nontemporal_store(
              (float)acc[mb][nb][g * 4 + j] * (sxq[g][j] * sc) + bs,
              &out[(size_t)row * NT + n]);
        }
    }
  }
}

// ---------- fallback (raw inputs, fused bf16 convert; round-1 structure) ----------
__global__ __launch_bounds__(256) void gemm_fallback(
    const float* __restrict__ Ap, const int* __restrict__ Bp,
    const float* __restrict__ scale, const float* __restrict__ bias,
    float* __restrict__ out) {
  __shared__ short ldsA[128 * 64];
  __shared__ short ldsB[128 * 64];
  const int tid = threadIdx.x;
  const int lane = tid & 63;
  const int wid = tid >> 6;
  const int nbn = NT / 128;
  const int cpx = ((MT / 128) * nbn) / 8;
  const int bid = blockIdx.x;
  const int wg = (bid & 7) * cpx + (bid >> 3);
  const int brow = (wg / nbn) * 128;
  const int bcol = (wg % nbn) * 128;
  const int wr = wid >> 1, wc = wid & 1;
  f32x4 acc[4][4] = {{{0.f, 0.f, 0.f, 0.f}}};
  const int srow = tid >> 3;
  const int sk8 = (tid & 7) * 8;
  for (int k0 = 0; k0 < KT; k0 += 64) {
    __syncthreads();
#pragma unroll
    for (int p = 0; p < 4; p++) {
      const int row = p * 32 + srow;
      const float* s = Ap + (size_t)(brow + row) * KT + k0 + sk8;
      f32x4 lo = *(const f32x4*)s;
      f32x4 hi = *(const f32x4*)(s + 4);
      short8 v;
#pragma unroll
      for (int j = 0; j < 4; j++) { v[j] = f2bf(lo[j]); v[4 + j] = f2bf(hi[j]); }
      int bo = (row * 64 + sk8) * 2;
      bo ^= ((row & 7) << 4);
      *(short8*)((char*)ldsA + bo) = v;
    }
#pragma unroll
    for (int p = 0; p < 4; p++) {
      const int row = p * 32 + srow;
      const int* s = Bp + (size_t)(bcol + row) * KT + k0 + sk8;
      i32x4 lo = *(const i32x4*)(s);
      i32x4 hi = *(const i32x4*)(s + 4);
      short8 v;
#pragma unroll
      for (int j = 0; j < 4; j++) { v[j] = f2bf((float)lo[j]); v[4 + j] = f2bf((float)hi[j]); }
      int bo = (row * 64 + sk8) * 2;
      bo ^= ((row & 7) << 4);
      *(short8*)((char*)ldsB + bo) = v;
    }
    __syncthreads();
#pragma unroll
    for (int kk = 0; kk < 2; kk++) {
      short8 af[4], bf2[4];
#pragma unroll
      for (int mi = 0; mi < 4; mi++) {
        const int row = wr * 64 + mi * 16 + (lane & 15);
        int bo = (row * 64 + kk * 32 + (lane >> 4) * 8) * 2;
        bo ^= ((row & 7) << 4);
        af[mi] = *(const short8*)((const char*)ldsA + bo);
      }
#pragma unroll
      for (int ni = 0; ni < 4; ni++) {
        const int row = wc * 64 + ni * 16 + (lane & 15);
        int bo = (row * 64 + kk * 32 + (lane >> 4) * 8) * 2;
        bo ^= ((row & 7) << 4);
        bf2[ni] = *(const short8*)((const char*)ldsB + bo);
      }
#pragma unroll
      for (int mi = 0; mi < 4; mi++)
#pragma unroll
        for (int ni = 0; ni < 4; ni++)
          acc[mi][ni] = __builtin_amdgcn_mfma_f32_16x16x32_bf16(af[mi], bf2[ni],
                                                                acc[mi][ni], 0, 0, 0);
    }
  }
#pragma unroll
  for (int ni = 0; ni < 4; ni++) {
    const int n = bcol + wc * 64 + ni * 16 + (lane & 15);
    const float sc = scale[n];
    const float bs = bias[n];
#pragma unroll
    for (int mi = 0; mi < 4; mi++) {
      const int m0 = brow + wr * 64 + mi * 16 + ((lane >> 4) << 2);
#pragma unroll
      for (int j = 0; j < 4; j++)
        out[(size_t)(m0 + j) * NT + n] = acc[mi][ni][j] * sc + bs;
    }
  }
}

extern "C" void kernel_launch(void* const* d_in, const int* in_sizes, int n_in,
                              void* d_out, int out_size, void* d_ws, size_t ws_size,
                              hipStream_t stream) {
  const float* x = (const float*)d_in[0];
  const int* w = (const int*)d_in[1];
  const float* scale = (const float*)d_in[2];
  const float* bias = (const float*)d_in[3];
  float* out = (float*)d_out;

  const size_t a_bytes = (size_t)MTILES * NKT * CHUNK_A;  // 32 MB
  const size_t b_bytes = (size_t)NTILES * NKT * CHUNK_B;  // 43 MB
  const size_t s_bytes = (size_t)MT * sizeof(float);      // 32 KB

  if (ws_size >= a_bytes + b_bytes + s_bytes) {
    char* aw = (char*)d_ws;
    char* bw = aw + a_bytes;
    float* sx = (float*)(bw + b_bytes);
    quant_x_kernel<<<dim3(MT), dim3(256), 0, stream>>>(x, aw, sx);
    cvt_w8_kernel<<<dim3(NT), dim3(256), 0, stream>>>(w, bw);
    gemm_nolds<<<dim3(MTILES * NTILES), dim3(256), 0, stream>>>(
        aw, bw, sx, scale, bias, out);
  } else {
    gemm_fallback<<<dim3((MT / 128) * (NT / 128)), dim3(256), 0, stream>>>(
        x, w, scale, bias, out);
  }
}

// Round 10
// 522.296 us; speedup vs baseline: 1.0343x; 1.0327x over previous
//
#include <hip/hip_runtime.h>
#include <hip/hip_bf16.h>
#include <stdint.h>

// CompressedLinear: out[M][N] = x[M][K] @ (w_int8[N][K] * scale[N])^T + bias[N]
// M=8192, K=4096, N=11008.
// R10: i8 GEMM, 32x32x32 MFMA. A: frag-linear LDS via global_load_lds. B:
// frag-linear d_ws -> VGPR direct. Block 256x128, 4 waves x 128x64, 2 blocks/CU.
// FIX vs R7: counted vmcnt(16) instead of end-of-tile vmcnt(0) drain — staging
// loads for t+2 stay in flight across both barriers (T4). 2 barriers/tile.

#define MT 8192
#define KT 4096
#define NT 11008
#define NKT 32              // K tiles of 128 (i8)
#define MTILES 32           // 8192/256
#define NTILES 86           // 11008/128
#define CHUNK_A 32768       // 256 rows x 128 k
#define CHUNK_B 16384       // 128 cols x 128 k

typedef __attribute__((ext_vector_type(8))) short short8;
typedef __attribute__((ext_vector_type(4))) float f32x4;
typedef __attribute__((ext_vector_type(4))) int i32x4;
typedef __attribute__((ext_vector_type(16))) int i32x16;
typedef __attribute__((ext_vector_type(16))) char char16;

static __device__ __forceinline__ short f2bf(float f) {
  union { float f; unsigned u; } c; c.f = f;
  unsigned u = c.u;
  return (short)((u + 0x7fffu + ((u >> 16) & 1u)) >> 16);  // RNE
}

// ---------------- packers: FRAG-LINEAR layout (R7-verified, absmax 2.25) ----------------
// A chunk (mt, kt) 32KB: frag(r32 0..7, s 0..3) at (r32*4+s)*1024; lane l holds
// row = mt*256 + r32*32 + (l&31), k = kt*128 + s*32 + (l>>5)*16 .. +15.
__global__ __launch_bounds__(256) void quant_x_kernel(const float* __restrict__ in,
                                                      char* __restrict__ Aws,
                                                      float* __restrict__ sx) {
  const int m = blockIdx.x;
  const int t = threadIdx.x;  // handles k = t*16 .. +15
  const float* row = in + (size_t)m * KT + t * 16;
  f32x4 v[4];
  float mx = 0.f;
#pragma unroll
  for (int i = 0; i < 4; i++) {
    v[i] = *(const f32x4*)(row + i * 4);
#pragma unroll
    for (int j = 0; j < 4; j++) mx = fmaxf(mx, fabsf(v[i][j]));
  }
#pragma unroll
  for (int off = 32; off; off >>= 1) mx = fmaxf(mx, __shfl_xor(mx, off));
  __shared__ float smx[4];
  if ((t & 63) == 0) smx[t >> 6] = mx;
  __syncthreads();
  mx = fmaxf(fmaxf(smx[0], smx[1]), fmaxf(smx[2], smx[3]));
  const float inv = 127.0f / mx;
  if (t == 0) sx[m] = mx * (1.0f / 127.0f);
  char16 q;
#pragma unroll
  for (int i = 0; i < 4; i++)
#pragma unroll
    for (int j = 0; j < 4; j++) q[i * 4 + j] = (char)(int)rintf(v[i][j] * inv);
  const int kt = t >> 3, s = (t >> 1) & 3, hi = t & 1;
  const int lane = (m & 31) | (hi << 5);
  const int r32 = (m >> 5) & 7;
  *(char16*)(Aws + ((size_t)(m >> 8) * NKT + kt) * CHUNK_A +
             (r32 * 4 + s) * 1024 + lane * 16) = q;
}

// B chunk (nt, kt) 16KB: frag(c32 0..3, s 0..3) at (c32*4+s)*1024; lane l holds
// col = nt*128 + c32*32 + (l&31), k = kt*128 + s*32 + (l>>5)*16 .. +15.
__global__ __launch_bounds__(256) void cvt_w8_kernel(const int* __restrict__ in,
                                                     char* __restrict__ Bws) {
  const int n = blockIdx.x;
  const int t = threadIdx.x;
  const int* s_ = in + (size_t)n * KT + t * 16;
  char16 q;
#pragma unroll
  for (int i = 0; i < 4; i++) {
    i32x4 a = *(const i32x4*)(s_ + i * 4);
#pragma unroll
    for (int j = 0; j < 4; j++) q[i * 4 + j] = (char)a[j];
  }
  const int kt = t >> 3, s = (t >> 1) & 3, hi = t & 1;
  const int lane = (n & 31) | (hi << 5);
  const int c32 = (n >> 5) & 3;
  *(char16*)(Bws + ((size_t)(n >> 7) * NKT + kt) * CHUNK_B +
             (c32 * 4 + s) * 1024 + lane * 16) = q;
}

// ---------------- 256x128 i8 GEMM, 4 waves x 128x64, 2 blocks/CU ----------------
// LDS: A only, 2 x 32KB = 64KB. Per K-tile (4 slices of K=32), per wave:
// 16 ds_read_b128 (lane-linear, zero conflicts) + 32 MFMA; B(t+1) 8 reg-loads
// at body top; A(t+2) 8 gload_lds between the barriers; vmcnt(16) keeps them
// in flight. Per-wave VMEM order: gld(t+1)x8 | B(t+1)x8 | gld(t+2)x8 ->
// vmcnt(16) == "A(t+1) landed", never a full drain until the last two tiles.

#define GLD(chunk, j, ldsbase)                                                   \
  __builtin_amdgcn_global_load_lds(                                              \
      (const __attribute__((address_space(1))) void*)((chunk) + (j) * 4096 +     \
                                                      tid * 16),                 \
      (__attribute__((address_space(3))) void*)((ldsbase) + (j) * 4096 +         \
                                                wid * 1024),                     \
      16, 0, 0)

#define GLDA(chunk, dst)                                       \
  do {                                                         \
    GLD(chunk, 0, dst); GLD(chunk, 1, dst);                    \
    GLD(chunk, 2, dst); GLD(chunk, 3, dst);                    \
    GLD(chunk, 4, dst); GLD(chunk, 5, dst);                    \
    GLD(chunk, 6, dst); GLD(chunk, 7, dst);                    \
  } while (0)

#define BAR asm volatile("s_barrier" ::: "memory")
#define VMC0 asm volatile("s_waitcnt vmcnt(0)" ::: "memory")
#define VMC16 asm volatile("s_waitcnt vmcnt(16)" ::: "memory")

#define LOADB(B_, src)                                         \
  do {                                                         \
    const char* bb_ = (src) + wc * 8192 + lane * 16;           \
    B_[0][0] = *(const i32x4*)(bb_);                           \
    B_[0][1] = *(const i32x4*)(bb_ + 1024);                    \
    B_[0][2] = *(const i32x4*)(bb_ + 2048);                    \
    B_[0][3] = *(const i32x4*)(bb_ + 3072);                    \
    B_[1][0] = *(const i32x4*)(bb_ + 4096);                    \
    B_[1][1] = *(const i32x4*)(bb_ + 5120);                    \
    B_[1][2] = *(const i32x4*)(bb_ + 6144);                    \
    B_[1][3] = *(const i32x4*)(bb_ + 7168);                    \
  } while (0)

// A reads: fully lane-linear (1024B per frag, lane*16) -> zero bank conflicts.
#define LDSL(LAp, s, aset)                                     \
  do {                                                         \
    const char* a_ = (LAp) + albase + (s) * 1024;              \
    aset[0] = *(const i32x4*)(a_);                             \
    aset[1] = *(const i32x4*)(a_ + 4096);                      \
    aset[2] = *(const i32x4*)(a_ + 8192);                      \
    aset[3] = *(const i32x4*)(a_ + 12288);                     \
  } while (0)

#define MMS(aset, BC, s)                                                       \
  do {                                                                         \
    __builtin_amdgcn_s_setprio(1);                                             \
    _Pragma("unroll") for (int mb = 0; mb < 4; mb++)                           \
        _Pragma("unroll") for (int nb = 0; nb < 2; nb++)                       \
            acc[mb][nb] = __builtin_amdgcn_mfma_i32_32x32x32_i8(               \
                aset[mb], BC[nb][s], acc[mb][nb], 0, 0, 0);                    \
    __builtin_amdgcn_s_setprio(0);                                             \
  } while (0)

#define TILE_BODY(BC, BN_)                                                     \
  {                                                                            \
    const char* LA = Lsm + (t & 1) * 32768;                                    \
    if (t + 1 < NKT) LOADB(BN_, Bch + CHUNK_B); /* B(t+1) -> regs (8 loads) */ \
    LDSL(LA, 1, a1);                                                           \
    MMS(a0, BC, 0);                                                            \
    LDSL(LA, 2, a0);                                                           \
    MMS(a1, BC, 1);                                                            \
    LDSL(LA, 3, a1);                                                           \
    MMS(a0, BC, 2);                                                            \
    MMS(a1, BC, 3);                                                            \
    BAR; /* all 4 waves done reading buf (t&1) */                              \
    if (t + 2 < NKT) { /* stage A(t+2) into the buffer just freed */           \
      char* dA = Lsm + (t & 1) * 32768;                                        \
      GLDA(Ach + 2 * CHUNK_A, dA);                                             \
    }                                                                          \
    if (t < NKT - 2) { VMC16; } else { VMC0; } /* A(t+1) landed; no drain */   \
    BAR; /* every wave's A(t+1) landed */                                      \
    if (t + 1 < NKT) {                                                         \
      const char* LAn = Lsm + ((t + 1) & 1) * 32768;                           \
      LDSL(LAn, 0, a0); /* heads of t+1 */                                     \
    }                                                                          \
    Ach += CHUNK_A;                                                            \
    Bch += CHUNK_B;                                                            \
    ++t;                                                                       \
  }

__global__ __launch_bounds__(256, 2) void gemm_cnt(
    const char* __restrict__ Aws, const char* __restrict__ Bws,
    const float* __restrict__ sx, const float* __restrict__ scale,
    const float* __restrict__ bias, float* __restrict__ out) {
  extern __shared__ char Lsm[];
  const int tid = threadIdx.x;
  const int lane = tid & 63;
  const int wid = tid >> 6;
  const int wr = wid >> 1;
  const int wc = wid & 1;

  // XCD mapping: nwg = 32*86 = 2752 = 8 XCD x 344; band = 4 mt x 86 nt.
  // mt-minor (4 consecutive share a B chunk), nt-major.
  const int bid = blockIdx.x;
  const int r = bid >> 3;
  const int mt = (bid & 7) * 4 + (r & 3);  // 0..31
  const int nt = r >> 2;                   // 0..85

  const char* Ach = Aws + (size_t)mt * NKT * CHUNK_A;
  const char* Bch = Bws + (size_t)nt * NKT * CHUNK_B;

  const int albase = wr * 16384 + lane * 16;  // frag-linear A base

  i32x16 acc[4][2] = {};
  i32x4 a0[4], a1[4], bA[2][4], bB[2][4];

  // ---- prologue: A(t0)->buf0 (drain once), then A(t1)->buf1 stays in flight ----
  {
    GLDA(Ach, Lsm);
    LOADB(bA, Bch);
    VMC0;
    BAR;
    GLDA(Ach + CHUNK_A, Lsm + 32768);
    LDSL(Lsm, 0, a0);
  }

  for (int t = 0; t < NKT;) {
    TILE_BODY(bA, bB);
    TILE_BODY(bB, bA);
  }

  // ---- epilogue: 32x32 C/D (m74/m101): col=lane&31, row=(reg&3)+8*(reg>>2)+4*(lane>>5) ----
  const int col_base = nt * 128 + wc * 64 + (lane & 31);
  const int row0 = mt * 256 + wr * 128 + ((lane >> 5) << 2);
#pragma unroll
  for (int mb = 0; mb < 4; mb++) {
    f32x4 sxq[4];
#pragma unroll
    for (int g = 0; g < 4; g++)
      sxq[g] = *(const f32x4*)(sx + row0 + mb * 32 + g * 8);
#pragma unroll
    for (int nb = 0; nb < 2; nb++) {
      const int n = col_base + nb * 32;
      const float sc = scale[n];
      const float bs = bias[n];
#pragma unroll
      for (int g = 0; g < 4; g++)
#pragma unroll
        for (int j = 0; j < 4; j++) {
          const int row = row0 + mb * 32 + g * 8 + j;
          out[(size_t)row * NT + n] =
              (float)acc[mb][nb][g * 4 + j] * (sxq[g][j] * sc) + bs;
        }
    }
  }
}

// ---------- fallback (raw inputs, fused bf16 convert; round-1 structure) ----------
__global__ __launch_bounds__(256) void gemm_fallback(
    const float* __restrict__ Ap, const int* __restrict__ Bp,
    const float* __restrict__ scale, const float* __restrict__ bias,
    float* __restrict__ out) {
  __shared__ short ldsA[128 * 64];
  __shared__ short ldsB[128 * 64];
  const int tid = threadIdx.x;
  const int lane = tid & 63;
  const int wid = tid >> 6;
  const int nbn = NT / 128;
  const int cpx = ((MT / 128) * nbn) / 8;
  const int bid = blockIdx.x;
  const int wg = (bid & 7) * cpx + (bid >> 3);
  const int brow = (wg / nbn) * 128;
  const int bcol = (wg % nbn) * 128;
  const int wr = wid >> 1, wc = wid & 1;
  f32x4 acc[4][4] = {{{0.f, 0.f, 0.f, 0.f}}};
  const int srow = tid >> 3;
  const int sk8 = (tid & 7) * 8;
  for (int k0 = 0; k0 < KT; k0 += 64) {
    __syncthreads();
#pragma unroll
    for (int p = 0; p < 4; p++) {
      const int row = p * 32 + srow;
      const float* s = Ap + (size_t)(brow + row) * KT + k0 + sk8;
      f32x4 lo = *(const f32x4*)s;
      f32x4 hi = *(const f32x4*)(s + 4);
      short8 v;
#pragma unroll
      for (int j = 0; j < 4; j++) { v[j] = f2bf(lo[j]); v[4 + j] = f2bf(hi[j]); }
      int bo = (row * 64 + sk8) * 2;
      bo ^= ((row & 7) << 4);
      *(short8*)((char*)ldsA + bo) = v;
    }
#pragma unroll
    for (int p = 0; p < 4; p++) {
      const int row = p * 32 + srow;
      const int* s = Bp + (size_t)(bcol + row) * KT + k0 + sk8;
      i32x4 lo = *(const i32x4*)(s);
      i32x4 hi = *(const i32x4*)(s + 4);
      short8 v;
#pragma unroll
      for (int j = 0; j < 4; j++) { v[j] = f2bf((float)lo[j]); v[4 + j] = f2bf((float)hi[j]); }
      int bo = (row * 64 + sk8) * 2;
      bo ^= ((row & 7) << 4);
      *(short8*)((char*)ldsB + bo) = v;
    }
    __syncthreads();
#pragma unroll
    for (int kk = 0; kk < 2; kk++) {
      short8 af[4], bf2[4];
#pragma unroll
      for (int mi = 0; mi < 4; mi++) {
        const int row = wr * 64 + mi * 16 + (lane & 15);
        int bo = (row * 64 + kk * 32 + (lane >> 4) * 8) * 2;
        bo ^= ((row & 7) << 4);
        af[mi] = *(const short8*)((const char*)ldsA + bo);
      }
#pragma unroll
      for (int ni = 0; ni < 4; ni++) {
        const int row = wc * 64 + ni * 16 + (lane & 15);
        int bo = (row * 64 + kk * 32 + (lane >> 4) * 8) * 2;
        bo ^= ((row & 7) << 4);
        bf2[ni] = *(const short8*)((const char*)ldsB + bo);
      }
#pragma unroll
      for (int mi = 0; mi < 4; mi++)
#pragma unroll
        for (int ni = 0; ni < 4; ni++)
          acc[mi][ni] = __builtin_amdgcn_mfma_f32_16x16x32_bf16(af[mi], bf2[ni],
                                                                acc[mi][ni], 0, 0, 0);
    }
  }
#pragma unroll
  for (int ni = 0; ni < 4; ni++) {
    const int n = bcol + wc * 64 + ni * 16 + (lane & 15);
    const float sc = scale[n];
    const float bs = bias[n];
#pragma unroll
    for (int mi = 0; mi < 4; mi++) {
      const int m0 = brow + wr * 64 + mi * 16 + ((lane >> 4) << 2);
#pragma unroll
      for (int j = 0; j < 4; j++)
        out[(size_t)(m0 + j) * NT + n] = acc[mi][ni][j] * sc + bs;
    }
  }
}

extern "C" void kernel_launch(void* const* d_in, const int* in_sizes, int n_in,
                              void* d_out, int out_size, void* d_ws, size_t ws_size,
                              hipStream_t stream) {
  const float* x = (const float*)d_in[0];
  const int* w = (const int*)d_in[1];
  const float* scale = (const float*)d_in[2];
  const float* bias = (const float*)d_in[3];
  float* out = (float*)d_out;

  const size_t a_bytes = (size_t)MTILES * NKT * CHUNK_A;  // 32 MB
  const size_t b_bytes = (size_t)NTILES * NKT * CHUNK_B;  // 43 MB
  const size_t s_bytes = (size_t)MT * sizeof(float);      // 32 KB

  if (ws_size >= a_bytes + b_bytes + s_bytes) {
    char* aw = (char*)d_ws;
    char* bw = aw + a_bytes;
    float* sx = (float*)(bw + b_bytes);
    quant_x_kernel<<<dim3(MT), dim3(256), 0, stream>>>(x, aw, sx);
    cvt_w8_kernel<<<dim3(NT), dim3(256), 0, stream>>>(w, bw);
    hipFuncSetAttribute((const void*)gemm_cnt,
                        hipFuncAttributeMaxDynamicSharedMemorySize, 65536);
    gemm_cnt<<<dim3(MTILES * NTILES), dim3(256), 65536, stream>>>(
        aw, bw, sx, scale, bias, out);
  } else {
    gemm_fallback<<<dim3((MT / 128) * (NT / 128)), dim3(256), 0, stream>>>(
        x, w, scale, bias, out);
  }
}

// Round 11
// 510.745 us; speedup vs baseline: 1.0577x; 1.0226x over previous
//
#include <hip/hip_runtime.h>
#include <hip/hip_bf16.h>
#include <stdint.h>

// CompressedLinear: out[M][N] = x[M][K] @ (w_int8[N][K] * scale[N])^T + bias[N]
// M=8192, K=4096, N=11008.
// R11: i8 GEMM, 32x32x32 MFMA, wave-tile 64x128 (A-LDS bytes/MFMA halved).
// Block 128x256, 4 waves (2wr x 2wc). A: frag-linear LDS via gload_lds (2 reads
// /slice/wave, zero conflicts). B: frag-linear global->VGPR, per-slice depth-4
// static pipeline (b[s] reloaded for t+1 right after slice s consumes it).
// wr-pairs read identical B addresses -> L1 absorbs the duplicate.

#define MT 8192
#define KT 4096
#define NT 11008
#define NKT 32              // K tiles of 128 (i8)
#define ATILES 64           // 8192/128 (A chunk rows = 128)
#define BTILES 43           // 11008/256 (B chunk cols = 256)
#define CHUNK_A 16384       // 128 rows x 128 k
#define CHUNK_B 32768       // 256 cols x 128 k

typedef __attribute__((ext_vector_type(8))) short short8;
typedef __attribute__((ext_vector_type(4))) float f32x4;
typedef __attribute__((ext_vector_type(4))) int i32x4;
typedef __attribute__((ext_vector_type(16))) int i32x16;
typedef __attribute__((ext_vector_type(16))) char char16;

static __device__ __forceinline__ short f2bf(float f) {
  union { float f; unsigned u; } c; c.f = f;
  unsigned u = c.u;
  return (short)((u + 0x7fffu + ((u >> 16) & 1u)) >> 16);  // RNE
}

// ---------------- packers: FRAG-LINEAR layout ----------------
// A chunk (mt,kt) 16KB: frag(r32 0..3, s 0..3) at (r32*4+s)*1024; lane l holds
// row = mt*128 + r32*32 + (l&31), k = kt*128 + s*32 + (l>>5)*16 .. +15.
__global__ __launch_bounds__(256) void quant_x_kernel(const float* __restrict__ in,
                                                      char* __restrict__ Aws,
                                                      float* __restrict__ sx) {
  const int m = blockIdx.x;
  const int t = threadIdx.x;  // handles k = t*16 .. +15
  const float* row = in + (size_t)m * KT + t * 16;
  f32x4 v[4];
  float mx = 0.f;
#pragma unroll
  for (int i = 0; i < 4; i++) {
    v[i] = *(const f32x4*)(row + i * 4);
#pragma unroll
    for (int j = 0; j < 4; j++) mx = fmaxf(mx, fabsf(v[i][j]));
  }
#pragma unroll
  for (int off = 32; off; off >>= 1) mx = fmaxf(mx, __shfl_xor(mx, off));
  __shared__ float smx[4];
  if ((t & 63) == 0) smx[t >> 6] = mx;
  __syncthreads();
  mx = fmaxf(fmaxf(smx[0], smx[1]), fmaxf(smx[2], smx[3]));
  const float inv = 127.0f / mx;
  if (t == 0) sx[m] = mx * (1.0f / 127.0f);
  char16 q;
#pragma unroll
  for (int i = 0; i < 4; i++)
#pragma unroll
    for (int j = 0; j < 4; j++) q[i * 4 + j] = (char)(int)rintf(v[i][j] * inv);
  const int kt = t >> 3, s = (t >> 1) & 3, hi = t & 1;
  const int lane = (m & 31) | (hi << 5);
  const int r32 = (m >> 5) & 3;
  *(char16*)(Aws + ((size_t)(m >> 7) * NKT + kt) * CHUNK_A +
             (r32 * 4 + s) * 1024 + lane * 16) = q;
}

// B chunk (nt,kt) 32KB: frag(c32 0..7, s 0..3) at (c32*4+s)*1024; lane l holds
// col = nt*256 + c32*32 + (l&31), k = kt*128 + s*32 + (l>>5)*16 .. +15.
__global__ __launch_bounds__(256) void cvt_w8_kernel(const int* __restrict__ in,
                                                     char* __restrict__ Bws) {
  const int n = blockIdx.x;
  const int t = threadIdx.x;
  const int* s_ = in + (size_t)n * KT + t * 16;
  char16 q;
#pragma unroll
  for (int i = 0; i < 4; i++) {
    i32x4 a = *(const i32x4*)(s_ + i * 4);
#pragma unroll
    for (int j = 0; j < 4; j++) q[i * 4 + j] = (char)a[j];
  }
  const int kt = t >> 3, s = (t >> 1) & 3, hi = t & 1;
  const int lane = (n & 31) | (hi << 5);
  const int c32 = (n >> 5) & 7;
  *(char16*)(Bws + ((size_t)(n >> 8) * NKT + kt) * CHUNK_B +
             (c32 * 4 + s) * 1024 + lane * 16) = q;
}

// ---------------- 128x256 i8 GEMM, 4 waves x 64x128, 2 blocks/CU ----------------
// LDS: A only, dbuf 2 x 16KB = 32KB. Per slice per wave: 2 A ds_read_b128
// (lane-linear) + 8 MFMA; B: 4 global dwordx4 per slice, depth-4 static regs.
// Per-wave VMEM order/tile: B(t+1) 16 | gldA(t+2) 4 -> vmcnt(20) retires
// gldA(t+1); loads never drain in steady state.

#define GLD(chunk, j, ldsbase)                                                   \
  __builtin_amdgcn_global_load_lds(                                              \
      (const __attribute__((address_space(1))) void*)((chunk) + (j) * 4096 +     \
                                                      tid * 16),                 \
      (__attribute__((address_space(3))) void*)((ldsbase) + (j) * 4096 +         \
                                                wid * 1024),                     \
      16, 0, 0)

#define GLDA(chunk, dst)                                       \
  do {                                                         \
    GLD(chunk, 0, dst); GLD(chunk, 1, dst);                    \
    GLD(chunk, 2, dst); GLD(chunk, 3, dst);                    \
  } while (0)

#define BAR asm volatile("s_barrier" ::: "memory")
#define VMC0 asm volatile("s_waitcnt vmcnt(0)" ::: "memory")
#define VMC20 asm volatile("s_waitcnt vmcnt(20)" ::: "memory")

// B slice load: 4 frags (nb 0..3) of tile (chunk idx ct), slice s.
#define LOADB_SL(B_, ct, s)                                    \
  do {                                                         \
    const char* bb_ = Bbase + (size_t)(ct)*CHUNK_B + (s)*1024; \
    B_[0] = *(const i32x4*)(bb_);                              \
    B_[1] = *(const i32x4*)(bb_ + 4096);                       \
    B_[2] = *(const i32x4*)(bb_ + 8192);                       \
    B_[3] = *(const i32x4*)(bb_ + 12288);                      \
  } while (0)

// A reads: 2 frags (mb 0..1), lane-linear -> zero bank conflicts.
#define LDSL(LAp, s, aset)                                     \
  do {                                                         \
    const char* a_ = (LAp) + albase + (s) * 1024;              \
    aset[0] = *(const i32x4*)(a_);                             \
    aset[1] = *(const i32x4*)(a_ + 4096);                      \
  } while (0)

#define MMS(aset, bsl)                                                         \
  do {                                                                         \
    __builtin_amdgcn_s_setprio(1);                                             \
    _Pragma("unroll") for (int mb = 0; mb < 2; mb++)                           \
        _Pragma("unroll") for (int nb = 0; nb < 4; nb++)                       \
            acc[mb][nb] = __builtin_amdgcn_mfma_i32_32x32x32_i8(               \
                aset[mb], bsl[nb], acc[mb][nb], 0, 0, 0);                      \
    __builtin_amdgcn_s_setprio(0);                                             \
  } while (0)

__global__ __launch_bounds__(256, 2) void gemm_r11(
    const char* __restrict__ Aws, const char* __restrict__ Bws,
    const float* __restrict__ sx, const float* __restrict__ scale,
    const float* __restrict__ bias, float* __restrict__ out) {
  extern __shared__ char Lsm[];
  const int tid = threadIdx.x;
  const int lane = tid & 63;
  const int wid = tid >> 6;
  const int wr = wid >> 1;
  const int wc = wid & 1;

  // XCD mapping: nwg = 64*43 = 2752 = 8 XCD x 344; band = 8 mt x 43 nt,
  // mt-minor (8 consecutive share a B chunk), nt-major. A band 4MB -> L2/XCD.
  const int bid = blockIdx.x;
  const int g8 = bid & 7;              // XCD id
  const int r8 = bid >> 3;             // 0..343
  const int mt = g8 * 8 + (r8 & 7);    // 0..63
  const int nt = r8 >> 3;              // 0..42

  const char* Ach = Aws + (size_t)mt * NKT * CHUNK_A;
  const char* Bbase = Bws + (size_t)nt * NKT * CHUNK_B + wc * 16384 + lane * 16;

  const int albase = wr * 8192 + lane * 16;  // frag-linear A base (2 frags @ +4096)

  i32x16 acc[2][4] = {};
  i32x4 a0[2], a1[2];
  i32x4 b0[4], b1[4], b2[4], b3[4];  // per-slice B, static names (rule #20)

  // ---- prologue: A(t0)->buf0, B(t0) all 4 slices; drain once; A(t1) in flight ----
  {
    GLDA(Ach, Lsm);
    LOADB_SL(b0, 0, 0);
    LOADB_SL(b1, 0, 1);
    LOADB_SL(b2, 0, 2);
    LOADB_SL(b3, 0, 3);
    VMC0;
    BAR;
    GLDA(Ach + CHUNK_A, Lsm + 16384);
    LDSL(Lsm, 0, a0);
  }

  for (int t = 0; t < NKT; ++t) {
    const char* LA = Lsm + (t & 1) * 16384;

    LDSL(LA, 1, a1);
    MMS(a0, b0);  LOADB_SL(b0, t + 1, 0);   // reload slice for t+1 (overrun at
    LDSL(LA, 2, a0);                        //  t=NKT-1 reads next-nt/sx: mapped)
    MMS(a1, b1);  LOADB_SL(b1, t + 1, 1);
    LDSL(LA, 3, a1);
    MMS(a0, b2);  LOADB_SL(b2, t + 1, 2);
    MMS(a1, b3);  LOADB_SL(b3, t + 1, 3);

    BAR;  // all 4 waves done reading A buf (t&1)
    if (t + 2 < NKT) {  // stage A(t+2) into the buffer just freed
      char* dA = Lsm + (t & 1) * 16384;
      GLDA(Ach + 2 * CHUNK_A, dA);
    }
    if (t < NKT - 2) { VMC20; } else { VMC0; }  // A(t+1) landed; no drain
    BAR;
    if (t + 1 < NKT) {
      const char* LAn = Lsm + ((t + 1) & 1) * 16384;
      LDSL(LAn, 0, a0);  // heads of t+1
    }
    Ach += CHUNK_A;
  }

  // ---- epilogue: 32x32 C/D (m74/m101): col=lane&31, row=(reg&3)+8*(reg>>2)+4*(lane>>5) ----
  const int col_base = nt * 256 + wc * 128 + (lane & 31);
  const int row0 = mt * 128 + wr * 64 + ((lane >> 5) << 2);
#pragma unroll
  for (int mb = 0; mb < 2; mb++) {
    f32x4 sxq[4];
#pragma unroll
    for (int g = 0; g < 4; g++)
      sxq[g] = *(const f32x4*)(sx + row0 + mb * 32 + g * 8);
#pragma unroll
    for (int nb = 0; nb < 4; nb++) {
      const int n = col_base + nb * 32;
      const float sc = scale[n];
      const float bs = bias[n];
#pragma unroll
      for (int g = 0; g < 4; g++)
#pragma unroll
        for (int j = 0; j < 4; j++) {
          const int row = row0 + mb * 32 + g * 8 + j;
          out[(size_t)row * NT + n] =
              (float)acc[mb][nb][g * 4 + j] * (sxq[g][j] * sc) + bs;
        }
    }
  }
}

// ---------- fallback (raw inputs, fused bf16 convert; round-1 structure) ----------
__global__ __launch_bounds__(256) void gemm_fallback(
    const float* __restrict__ Ap, const int* __restrict__ Bp,
    const float* __restrict__ scale, const float* __restrict__ bias,
    float* __restrict__ out) {
  __shared__ short ldsA[128 * 64];
  __shared__ short ldsB[128 * 64];
  const int tid = threadIdx.x;
  const int lane = tid & 63;
  const int wid = tid >> 6;
  const int nbn = NT / 128;
  const int cpx = ((MT / 128) * nbn) / 8;
  const int bid = blockIdx.x;
  const int wg = (bid & 7) * cpx + (bid >> 3);
  const int brow = (wg / nbn) * 128;
  const int bcol = (wg % nbn) * 128;
  const int wr = wid >> 1, wc = wid & 1;
  f32x4 acc[4][4] = {{{0.f, 0.f, 0.f, 0.f}}};
  const int srow = tid >> 3;
  const int sk8 = (tid & 7) * 8;
  for (int k0 = 0; k0 < KT; k0 += 64) {
    __syncthreads();
#pragma unroll
    for (int p = 0; p < 4; p++) {
      const int row = p * 32 + srow;
      const float* s = Ap + (size_t)(brow + row) * KT + k0 + sk8;
      f32x4 lo = *(const f32x4*)s;
      f32x4 hi = *(const f32x4*)(s + 4);
      short8 v;
#pragma unroll
      for (int j = 0; j < 4; j++) { v[j] = f2bf(lo[j]); v[4 + j] = f2bf(hi[j]); }
      int bo = (row * 64 + sk8) * 2;
      bo ^= ((row & 7) << 4);
      *(short8*)((char*)ldsA + bo) = v;
    }
#pragma unroll
    for (int p = 0; p < 4; p++) {
      const int row = p * 32 + srow;
      const int* s = Bp + (size_t)(bcol + row) * KT + k0 + sk8;
      i32x4 lo = *(const i32x4*)(s);
      i32x4 hi = *(const i32x4*)(s + 4);
      short8 v;
#pragma unroll
      for (int j = 0; j < 4; j++) { v[j] = f2bf((float)lo[j]); v[4 + j] = f2bf((float)hi[j]); }
      int bo = (row * 64 + sk8) * 2;
      bo ^= ((row & 7) << 4);
      *(short8*)((char*)ldsB + bo) = v;
    }
    __syncthreads();
#pragma unroll
    for (int kk = 0; kk < 2; kk++) {
      short8 af[4], bf2[4];
#pragma unroll
      for (int mi = 0; mi < 4; mi++) {
        const int row = wr * 64 + mi * 16 + (lane & 15);
        int bo = (row * 64 + kk * 32 + (lane >> 4) * 8) * 2;
        bo ^= ((row & 7) << 4);
        af[mi] = *(const short8*)((const char*)ldsA + bo);
      }
#pragma unroll
      for (int ni = 0; ni < 4; ni++) {
        const int row = wc * 64 + ni * 16 + (lane & 15);
        int bo = (row * 64 + kk * 32 + (lane >> 4) * 8) * 2;
        bo ^= ((row & 7) << 4);
        bf2[ni] = *(const short8*)((const char*)ldsB + bo);
      }
#pragma unroll
      for (int mi = 0; mi < 4; mi++)
#pragma unroll
        for (int ni = 0; ni < 4; ni++)
          acc[mi][ni] = __builtin_amdgcn_mfma_f32_16x16x32_bf16(af[mi], bf2[ni],
                                                                acc[mi][ni], 0, 0, 0);
    }
  }
#pragma unroll
  for (int ni = 0; ni < 4; ni++) {
    const int n = bcol + wc * 64 + ni * 16 + (lane & 15);
    const float sc = scale[n];
    const float bs = bias[n];
#pragma unroll
    for (int mi = 0; mi < 4; mi++) {
      const int m0 = brow + wr * 64 + mi * 16 + ((lane >> 4) << 2);
#pragma unroll
      for (int j = 0; j < 4; j++)
        out[(size_t)(m0 + j) * NT + n] = acc[mi][ni][j] * sc + bs;
    }
  }
}

extern "C" void kernel_launch(void* const* d_in, const int* in_sizes, int n_in,
                              void* d_out, int out_size, void* d_ws, size_t ws_size,
                              hipStream_t stream) {
  const float* x = (const float*)d_in[0];
  const int* w = (const int*)d_in[1];
  const float* scale = (const float*)d_in[2];
  const float* bias = (const float*)d_in[3];
  float* out = (float*)d_out;

  const size_t a_bytes = (size_t)ATILES * NKT * CHUNK_A;  // 32 MB
  const size_t b_bytes = (size_t)BTILES * NKT * CHUNK_B;  // 43 MB
  const size_t s_bytes = (size_t)MT * sizeof(float);      // 32 KB

  if (ws_size >= a_bytes + b_bytes + s_bytes) {
    char* aw = (char*)d_ws;
    char* bw = aw + a_bytes;
    float* sx = (float*)(bw + b_bytes);
    quant_x_kernel<<<dim3(MT), dim3(256), 0, stream>>>(x, aw, sx);
    cvt_w8_kernel<<<dim3(NT), dim3(256), 0, stream>>>(w, bw);
    hipFuncSetAttribute((const void*)gemm_r11,
                        hipFuncAttributeMaxDynamicSharedMemorySize, 32768);
    gemm_r11<<<dim3(ATILES * BTILES), dim3(256), 32768, stream>>>(
        aw, bw, sx, scale, bias, out);
  } else {
    gemm_fallback<<<dim3((MT / 128) * (NT / 128)), dim3(256), 0, stream>>>(
        x, w, scale, bias, out);
  }
}